// Round 1
// 175.197 us; speedup vs baseline: 1.1366x; 1.1366x over previous
//
#include <hip/hip_runtime.h>

// SSIM loss, fused. Input: enhanced, target fp32 [16,3,512,512]. Output: scalar fp32.
// V2: horizontal pass reads directly from global (float4, L1/L2-served halo),
// single padded LDS buffer for the 5 h-filtered channels, all LDS ops are b128
// with immediate offsets, vertical pass = 1 (row x 4-col) item per thread.

#define TILE_W 64
#define TILE_H 16
#define HALO 3
#define IN_H (TILE_H + 2 * HALO)      // 22
#define H_STRIDE 68                   // 64 + 4: keeps 16B alignment, rotates banks by 4/row
#define CH_STRIDE (IN_H * H_STRIDE)   // 1496 floats = 5984 B per channel
#define IMG_H 512
#define IMG_W 512
#define NPLANES 48                    // 16 * 3
#define SSIM_C1 1.0e-4f
#define SSIM_C2 9.0e-4f

__device__ __constant__ float c_g[7] = {
    0.03663284536f, 0.11128076166f, 0.21674531251f, 0.27068216094f,
    0.21674531251f, 0.11128076166f, 0.03663284536f};

// Aligned float4 load with zero fill outside [0, IMG_W). col is a multiple of 4.
__device__ __forceinline__ float4 ld4z(const float* __restrict__ row, int col) {
  if (col >= 0 && col + 3 < IMG_W) {
    return *reinterpret_cast<const float4*>(row + col);
  }
  float4 v;
  v.x = ((unsigned)(col + 0) < IMG_W) ? row[col + 0] : 0.f;
  v.y = ((unsigned)(col + 1) < IMG_W) ? row[col + 1] : 0.f;
  v.z = ((unsigned)(col + 2) < IMG_W) ? row[col + 2] : 0.f;
  v.w = ((unsigned)(col + 3) < IMG_W) ? row[col + 3] : 0.f;
  return v;
}

__global__ __launch_bounds__(256, 5) void ssim_tile_kernel(
    const float* __restrict__ x, const float* __restrict__ y,
    float* __restrict__ partial) {
  // 5 channels (mu1, mu2, xx, yy, xy) of horizontally-filtered rows.
  __shared__ __align__(16) float hbuf[5 * CH_STRIDE];  // 29,920 B -> 5 blocks/CU

  const int tid = threadIdx.x;
  const int plane = blockIdx.z;
  const float* __restrict__ xp = x + (size_t)plane * (IMG_H * IMG_W);
  const float* __restrict__ yp = y + (size_t)plane * (IMG_H * IMG_W);
  const int y0 = blockIdx.y * TILE_H - HALO;
  const int cbase = blockIdx.x * TILE_W - 4;  // first reg col (output col - 4)

  // ---- Horizontal 7-tap pass: each item = (row, 4 adjacent output cols). ----
  // Inputs come straight from global: 3 aligned float4 per side; 12-float
  // window [base .. base+11], taps for output j use indices j+1 .. j+7.
  for (int item = tid; item < IN_H * 16; item += 256) {
    const int hr = item >> 4;
    const int cg = item & 15;
    const int gy = y0 + hr;
    float xin[12], yin[12];
    if ((unsigned)gy < IMG_H) {
      const float* xr = xp + (size_t)gy * IMG_W;
      const float* yr = yp + (size_t)gy * IMG_W;
      const int base = cbase + 4 * cg;
#pragma unroll
      for (int v = 0; v < 3; ++v) {
        const float4 a = ld4z(xr, base + 4 * v);
        const float4 b = ld4z(yr, base + 4 * v);
        xin[4 * v + 0] = a.x; xin[4 * v + 1] = a.y;
        xin[4 * v + 2] = a.z; xin[4 * v + 3] = a.w;
        yin[4 * v + 0] = b.x; yin[4 * v + 1] = b.y;
        yin[4 * v + 2] = b.z; yin[4 * v + 3] = b.w;
      }
    } else {
#pragma unroll
      for (int i = 0; i < 12; ++i) { xin[i] = 0.f; yin[i] = 0.f; }
    }
    float a1[4] = {0.f, 0.f, 0.f, 0.f};
    float a2[4] = {0.f, 0.f, 0.f, 0.f};
    float axx[4] = {0.f, 0.f, 0.f, 0.f};
    float ayy[4] = {0.f, 0.f, 0.f, 0.f};
    float axy[4] = {0.f, 0.f, 0.f, 0.f};
#pragma unroll
    for (int k = 0; k < 7; ++k) {
      const float gk = c_g[k];
#pragma unroll
      for (int j = 0; j < 4; ++j) {
        const float xv = xin[k + 1 + j];
        const float yv = yin[k + 1 + j];
        const float tx = gk * xv;
        const float ty = gk * yv;
        a1[j] += tx;
        a2[j] += ty;
        axx[j] = fmaf(tx, xv, axx[j]);
        ayy[j] = fmaf(ty, yv, ayy[j]);
        axy[j] = fmaf(tx, yv, axy[j]);
      }
    }
    float* hb = &hbuf[hr * H_STRIDE + 4 * cg];
    *reinterpret_cast<float4*>(hb + 0 * CH_STRIDE) =
        make_float4(a1[0], a1[1], a1[2], a1[3]);
    *reinterpret_cast<float4*>(hb + 1 * CH_STRIDE) =
        make_float4(a2[0], a2[1], a2[2], a2[3]);
    *reinterpret_cast<float4*>(hb + 2 * CH_STRIDE) =
        make_float4(axx[0], axx[1], axx[2], axx[3]);
    *reinterpret_cast<float4*>(hb + 3 * CH_STRIDE) =
        make_float4(ayy[0], ayy[1], ayy[2], ayy[3]);
    *reinterpret_cast<float4*>(hb + 4 * CH_STRIDE) =
        make_float4(axy[0], axy[1], axy[2], axy[3]);
  }
  __syncthreads();

  // ---- Vertical 7-tap pass + SSIM map: one (row, 4-col) item per thread. ----
  const int r = tid >> 4;
  const int c = (tid & 15) * 4;
  const float* hb = &hbuf[r * H_STRIDE + c];
  float4 m1 = {0.f, 0.f, 0.f, 0.f};
  float4 m2 = {0.f, 0.f, 0.f, 0.f};
  float4 sxx = {0.f, 0.f, 0.f, 0.f};
  float4 syy = {0.f, 0.f, 0.f, 0.f};
  float4 sxy = {0.f, 0.f, 0.f, 0.f};
#pragma unroll
  for (int k = 0; k < 7; ++k) {
    const float gk = c_g[k];
    const float4 v1 = *reinterpret_cast<const float4*>(hb + k * H_STRIDE + 0 * CH_STRIDE);
    const float4 v2 = *reinterpret_cast<const float4*>(hb + k * H_STRIDE + 1 * CH_STRIDE);
    const float4 vxx = *reinterpret_cast<const float4*>(hb + k * H_STRIDE + 2 * CH_STRIDE);
    const float4 vyy = *reinterpret_cast<const float4*>(hb + k * H_STRIDE + 3 * CH_STRIDE);
    const float4 vxy = *reinterpret_cast<const float4*>(hb + k * H_STRIDE + 4 * CH_STRIDE);
    m1.x = fmaf(gk, v1.x, m1.x);  m1.y = fmaf(gk, v1.y, m1.y);
    m1.z = fmaf(gk, v1.z, m1.z);  m1.w = fmaf(gk, v1.w, m1.w);
    m2.x = fmaf(gk, v2.x, m2.x);  m2.y = fmaf(gk, v2.y, m2.y);
    m2.z = fmaf(gk, v2.z, m2.z);  m2.w = fmaf(gk, v2.w, m2.w);
    sxx.x = fmaf(gk, vxx.x, sxx.x);  sxx.y = fmaf(gk, vxx.y, sxx.y);
    sxx.z = fmaf(gk, vxx.z, sxx.z);  sxx.w = fmaf(gk, vxx.w, sxx.w);
    syy.x = fmaf(gk, vyy.x, syy.x);  syy.y = fmaf(gk, vyy.y, syy.y);
    syy.z = fmaf(gk, vyy.z, syy.z);  syy.w = fmaf(gk, vyy.w, syy.w);
    sxy.x = fmaf(gk, vxy.x, sxy.x);  sxy.y = fmaf(gk, vxy.y, sxy.y);
    sxy.z = fmaf(gk, vxy.z, sxy.z);  sxy.w = fmaf(gk, vxy.w, sxy.w);
  }

  float acc = 0.f;
  {
    const float mu1[4] = {m1.x, m1.y, m1.z, m1.w};
    const float mu2[4] = {m2.x, m2.y, m2.z, m2.w};
    const float exx[4] = {sxx.x, sxx.y, sxx.z, sxx.w};
    const float eyy[4] = {syy.x, syy.y, syy.z, syy.w};
    const float exy[4] = {sxy.x, sxy.y, sxy.z, sxy.w};
#pragma unroll
    for (int j = 0; j < 4; ++j) {
      const float mu1sq = mu1[j] * mu1[j];
      const float mu2sq = mu2[j] * mu2[j];
      const float mu12 = mu1[j] * mu2[j];
      const float s1 = exx[j] - mu1sq;
      const float s2 = eyy[j] - mu2sq;
      const float s12 = exy[j] - mu12;
      const float num = (2.f * mu12 + SSIM_C1) * (2.f * s12 + SSIM_C2);
      const float den = (mu1sq + mu2sq + SSIM_C1) * (s1 + s2 + SSIM_C2);
      acc += num / den;
    }
  }

  // Block reduction: wave64 shuffle tree, then LDS across 4 waves.
#pragma unroll
  for (int off = 32; off > 0; off >>= 1) acc += __shfl_down(acc, off, 64);
  __shared__ float wsum[4];
  if ((tid & 63) == 0) wsum[tid >> 6] = acc;
  __syncthreads();
  if (tid == 0) {
    const float s = wsum[0] + wsum[1] + wsum[2] + wsum[3];
    partial[(size_t)blockIdx.z * gridDim.x * gridDim.y +
            (size_t)blockIdx.y * gridDim.x + blockIdx.x] = s;
  }
}

__global__ __launch_bounds__(1024) void ssim_reduce_kernel(
    const float* __restrict__ partial, int n, float* __restrict__ out) {
  float acc = 0.f;
  const int nv = n >> 2;  // n = 12288, divisible by 4
  const float4* __restrict__ p4 = reinterpret_cast<const float4*>(partial);
  for (int i = threadIdx.x; i < nv; i += 1024) {
    const float4 v = p4[i];
    acc += (v.x + v.y) + (v.z + v.w);
  }
#pragma unroll
  for (int off = 32; off > 0; off >>= 1) acc += __shfl_down(acc, off, 64);
  __shared__ float wsum[16];
  if ((threadIdx.x & 63) == 0) wsum[threadIdx.x >> 6] = acc;
  __syncthreads();
  if (threadIdx.x == 0) {
    float s = 0.f;
#pragma unroll
    for (int w = 0; w < 16; ++w) s += wsum[w];
    out[0] = 1.f - s * (1.f / (float)(NPLANES * IMG_H * IMG_W));
  }
}

extern "C" void kernel_launch(void* const* d_in, const int* in_sizes, int n_in,
                              void* d_out, int out_size, void* d_ws, size_t ws_size,
                              hipStream_t stream) {
  const float* enhanced = (const float*)d_in[0];
  const float* target = (const float*)d_in[1];
  float* out = (float*)d_out;
  float* partial = (float*)d_ws;

  dim3 grid(IMG_W / TILE_W, IMG_H / TILE_H, NPLANES);  // 8 x 32 x 48 = 12288
  dim3 block(256, 1, 1);
  ssim_tile_kernel<<<grid, block, 0, stream>>>(enhanced, target, partial);

  const int nblocks = (IMG_W / TILE_W) * (IMG_H / TILE_H) * NPLANES;
  ssim_reduce_kernel<<<1, 1024, 0, stream>>>(partial, nblocks, out);
}